// Round 1
// baseline (313.873 us; speedup 1.0000x reference)
//
#include <hip/hip_runtime.h>
#include <hip/hip_bf16.h>

#define L_DIM 128
#define N_PER_B 65536
#define BATCH 8

typedef __attribute__((ext_vector_type(8))) short bf16x8;
typedef __attribute__((ext_vector_type(4))) short bf16x4;
typedef __attribute__((ext_vector_type(4))) float f32x4;

__device__ __forceinline__ short f2bf(float f) {
    unsigned u = __float_as_uint(f);
    u += 0x7fffu + ((u >> 16) & 1u);   // round-to-nearest-even
    return (short)(u >> 16);
}

// ---------------- Kernel 1: energy[b,l,m] = sum_n q[b,n,l]*q[b,n,m] ----------------
#define K1_CHUNK 1024
#define K1_S 64

__global__ __launch_bounds__(256) void energy_kernel(const float* __restrict__ x,
                                                     float* __restrict__ energy) {
    const int wg = blockIdx.x;
    const int chunks = N_PER_B / K1_CHUNK;  // 64
    const int b = wg / chunks;
    const int chunk = wg % chunks;
    const float* q = x + (size_t)b * N_PER_B * L_DIM + (size_t)chunk * K1_CHUNK * L_DIM;

    // lds[l][n] bf16, byte addr = l*128 + n*2, swizzled ^((l&7)<<4)
    __shared__ short lds[L_DIM * K1_S];

    const int tid = threadIdx.x;
    const int wid = tid >> 6;
    const int lane = tid & 63;
    const int lr = lane & 15;
    const int lg = lane >> 4;

    f32x4 acc[2][8];
#pragma unroll
    for (int a = 0; a < 2; ++a)
#pragma unroll
        for (int m = 0; m < 8; ++m) acc[a][m] = (f32x4)0.f;

    for (int s = 0; s < K1_CHUNK; s += K1_S) {
        __syncthreads();
        // stage: transpose 64n x 128l fp32 -> lds[l][n] bf16 (4x4 register transpose)
#pragma unroll
        for (int it = 0; it < 2; ++it) {
            int quad = tid + it * 256;
            int n0 = (quad >> 5) << 2;  // 0..60
            int l0 = (quad & 31) << 2;  // 0..124
            float r[4][4];
            *(float4*)&r[0][0] = *(const float4*)(q + (size_t)(s + n0 + 0) * L_DIM + l0);
            *(float4*)&r[1][0] = *(const float4*)(q + (size_t)(s + n0 + 1) * L_DIM + l0);
            *(float4*)&r[2][0] = *(const float4*)(q + (size_t)(s + n0 + 2) * L_DIM + l0);
            *(float4*)&r[3][0] = *(const float4*)(q + (size_t)(s + n0 + 3) * L_DIM + l0);
#pragma unroll
            for (int i = 0; i < 4; ++i) {
                int l = l0 + i;
                bf16x4 p;
                p[0] = f2bf(r[0][i]);
                p[1] = f2bf(r[1][i]);
                p[2] = f2bf(r[2][i]);
                p[3] = f2bf(r[3][i]);
                int byte = l * (K1_S * 2) + n0 * 2;
                byte ^= (l & 7) << 4;
                *(bf16x4*)((char*)lds + byte) = p;
            }
        }
        __syncthreads();
#pragma unroll
        for (int ks = 0; ks < K1_S / 32; ++ks) {
            // frag f[i]: element j = q[n = ks*32 + lg*8 + j][l = i*16 + lr]
            bf16x8 f[8];
            int kbyte = ks * 64 + (lg << 4);
#pragma unroll
            for (int i = 0; i < 8; ++i) {
                int l = i * 16 + lr;
                int byte = l * (K1_S * 2) + kbyte;
                byte ^= (l & 7) << 4;
                f[i] = *(bf16x8*)((char*)lds + byte);
            }
#pragma unroll
            for (int a = 0; a < 2; ++a) {
                int tl = wid * 2 + a;
#pragma unroll
                for (int m = 0; m < 8; ++m)
                    acc[a][m] = __builtin_amdgcn_mfma_f32_16x16x32_bf16(f[tl], f[m], acc[a][m], 0, 0, 0);
            }
        }
    }

    float* eb = energy + (size_t)b * L_DIM * L_DIM;
#pragma unroll
    for (int a = 0; a < 2; ++a) {
        int row0 = (wid * 2 + a) * 16 + lg * 4;
#pragma unroll
        for (int m = 0; m < 8; ++m)
#pragma unroll
            for (int r2 = 0; r2 < 4; ++r2)
                atomicAdd(&eb[(size_t)(row0 + r2) * L_DIM + m * 16 + lr], acc[a][m][r2]);
    }
}

// ---------------- Kernel 2: softmax over m; write attnT[b][m][l] as bf16 ----------------
__global__ __launch_bounds__(64) void softmax_kernel(const float* __restrict__ energy,
                                                     short* __restrict__ attnT) {
    const int row = blockIdx.x;  // b*128 + l
    const int b = row >> 7;
    const int l = row & 127;
    const float* e = energy + (size_t)row * L_DIM;
    const int t = threadIdx.x;
    float v0 = e[t];
    float v1 = e[t + 64];
    float mx = fmaxf(v0, v1);
#pragma unroll
    for (int o = 32; o > 0; o >>= 1) mx = fmaxf(mx, __shfl_xor(mx, o));
    float e0 = __expf(v0 - mx);
    float e1 = __expf(v1 - mx);
    float sm = e0 + e1;
#pragma unroll
    for (int o = 32; o > 0; o >>= 1) sm += __shfl_xor(sm, o);
    float inv = 1.0f / sm;
    short* at = attnT + (size_t)b * L_DIM * L_DIM;
    at[(size_t)t * L_DIM + l] = f2bf(e0 * inv);
    at[(size_t)(t + 64) * L_DIM + l] = f2bf(e1 * inv);
}

// ---------------- Kernel 3: out[b,n,m] = sum_l q[b,n,l]*attn[b,l,m] ----------------
#define K3_ROWS 128

__global__ __launch_bounds__(256) void pv_kernel(const float* __restrict__ x,
                                                 const short* __restrict__ attnT,
                                                 float* __restrict__ out) {
    const int wg = blockIdx.x;
    const int chunks = N_PER_B / K3_ROWS;  // 512
    const int b = wg / chunks;
    const int chunk = wg % chunks;
    const float* q = x + (size_t)b * N_PER_B * L_DIM + (size_t)chunk * K3_ROWS * L_DIM;
    float* o = out + (size_t)b * N_PER_B * L_DIM + (size_t)chunk * K3_ROWS * L_DIM;
    const short* at = attnT + (size_t)b * L_DIM * L_DIM;

    // ldsA[n][l], ldsB[m][l]; byte = r*256 + l*2, swizzled ^((r&7)<<4)
    __shared__ short ldsA[K3_ROWS * L_DIM];
    __shared__ short ldsB[L_DIM * L_DIM];

    const int tid = threadIdx.x;
    const int wid = tid >> 6;
    const int lane = tid & 63;
    const int lr = lane & 15;
    const int lg = lane >> 4;

#pragma unroll
    for (int it = 0; it < 8; ++it) {
        int idx = tid + it * 256;
        int n = idx >> 4;            // 0..127
        int l0 = (idx & 15) << 3;    // 0..120
        float4 ra = *(const float4*)(q + (size_t)n * L_DIM + l0);
        float4 rb = *(const float4*)(q + (size_t)n * L_DIM + l0 + 4);
        bf16x8 p;
        p[0] = f2bf(ra.x); p[1] = f2bf(ra.y); p[2] = f2bf(ra.z); p[3] = f2bf(ra.w);
        p[4] = f2bf(rb.x); p[5] = f2bf(rb.y); p[6] = f2bf(rb.z); p[7] = f2bf(rb.w);
        int byte = n * 256 + l0 * 2;
        byte ^= (n & 7) << 4;
        *(bf16x8*)((char*)ldsA + byte) = p;

        bf16x8 v = *(const bf16x8*)(at + (size_t)n * L_DIM + l0);
        int byteb = n * 256 + l0 * 2;
        byteb ^= (n & 7) << 4;
        *(bf16x8*)((char*)ldsB + byteb) = v;
    }
    __syncthreads();

    f32x4 acc[2][8];
#pragma unroll
    for (int a = 0; a < 2; ++a)
#pragma unroll
        for (int m = 0; m < 8; ++m) acc[a][m] = (f32x4)0.f;

#pragma unroll
    for (int ks = 0; ks < 4; ++ks) {
        int kbyte = ks * 64 + (lg << 4);
        bf16x8 afr[2], bfr[8];
#pragma unroll
        for (int a = 0; a < 2; ++a) {
            int n = (wid * 2 + a) * 16 + lr;
            int byte = n * 256 + kbyte;
            byte ^= (n & 7) << 4;
            afr[a] = *(bf16x8*)((char*)ldsA + byte);
        }
#pragma unroll
        for (int m = 0; m < 8; ++m) {
            int mm = m * 16 + lr;
            int byte = mm * 256 + kbyte;
            byte ^= (mm & 7) << 4;
            bfr[m] = *(bf16x8*)((char*)ldsB + byte);
        }
#pragma unroll
        for (int a = 0; a < 2; ++a)
#pragma unroll
            for (int m = 0; m < 8; ++m)
                acc[a][m] = __builtin_amdgcn_mfma_f32_16x16x32_bf16(afr[a], bfr[m], acc[a][m], 0, 0, 0);
    }

#pragma unroll
    for (int a = 0; a < 2; ++a) {
        int row0 = (wid * 2 + a) * 16 + lg * 4;
#pragma unroll
        for (int m = 0; m < 8; ++m)
#pragma unroll
            for (int r2 = 0; r2 < 4; ++r2)
                o[(size_t)(row0 + r2) * L_DIM + m * 16 + lr] = acc[a][m][r2];
    }
}

extern "C" void kernel_launch(void* const* d_in, const int* in_sizes, int n_in,
                              void* d_out, int out_size, void* d_ws, size_t ws_size,
                              hipStream_t stream) {
    const float* x = (const float*)d_in[0];
    float* out = (float*)d_out;
    float* energy = (float*)d_ws;                                               // 512 KB
    short* attnT = (short*)((char*)d_ws + (size_t)BATCH * L_DIM * L_DIM * 4);   // 256 KB

    hipMemsetAsync(energy, 0, (size_t)BATCH * L_DIM * L_DIM * sizeof(float), stream);
    hipLaunchKernelGGL(energy_kernel, dim3(BATCH * (N_PER_B / K1_CHUNK)), dim3(256), 0, stream,
                       x, energy);
    hipLaunchKernelGGL(softmax_kernel, dim3(BATCH * L_DIM), dim3(64), 0, stream,
                       energy, attnT);
    hipLaunchKernelGGL(pv_kernel, dim3(BATCH * (N_PER_B / K3_ROWS)), dim3(256), 0, stream,
                       x, attnT, out);
}

// Round 2
// 194.589 us; speedup vs baseline: 1.6130x; 1.6130x over previous
//
#include <hip/hip_runtime.h>
#include <hip/hip_bf16.h>

#define L_DIM 128
#define N_PER_B 65536
#define BATCH 8

typedef __attribute__((ext_vector_type(8))) short bf16x8;
typedef __attribute__((ext_vector_type(4))) float f32x4;

__device__ __forceinline__ short f2bf(float f) {
    unsigned u = __float_as_uint(f);
    u += 0x7fffu + ((u >> 16) & 1u);   // round-to-nearest-even
    return (short)(u >> 16);
}

// packed f32x2 -> bf16x2 (RNE), maps to v_cvt_pk_bf16_f32
__device__ __forceinline__ unsigned pk2(float a, float b) {
    union { __hip_bfloat162 h; unsigned u; } cvt;
    cvt.h = __float22bfloat162_rn(float2{a, b});
    return cvt.u;
}

// ---------------- Kernel 1: energy[b,l,m] = sum_n q[b,n,l]*q[b,n,m] ----------------
// 512 threads = 8 waves; each wave owns one 16-row block of energy.
// LDS: [l][n] bf16 tile (128 l x 64 n), byte = l*128 + n*2, XOR key ((l^(l>>2))&7)<<4
#define K1_CHUNK 1024
#define K1_S 64

__global__ __launch_bounds__(512, 4) void energy_kernel(const float* __restrict__ x,
                                                        float* __restrict__ energy) {
    const int wg = blockIdx.x;
    const int b = wg >> 6;          // 64 chunks per batch
    const int chunk = wg & 63;
    const float* q = x + (size_t)b * N_PER_B * L_DIM + (size_t)chunk * K1_CHUNK * L_DIM;

    __shared__ short lds[L_DIM * K1_S];   // 16 KB

    const int tid = threadIdx.x;
    const int w = tid >> 6;         // wave 0..7
    const int lane = tid & 63;
    const int lr = lane & 15;
    const int lg = lane >> 4;

    // ---- staging coords (hoisted) ----
    const int n0 = ((lane >> 4) + (w & 3) * 4) * 4;         // 0..60
    const int l0 = (lane & 15) * 4 + (w >> 2) * 64;         // 0..124
    const float* gp = q + (size_t)n0 * L_DIM + l0;

    int wb[4];
#pragma unroll
    for (int c = 0; c < 4; ++c) {
        int l = l0 + c;
        wb[c] = (l * (K1_S * 2) + n0 * 2) ^ (((l ^ (l >> 2)) & 7) << 4);
    }

    // ---- fragment read addrs (hoisted): f[i][j] = q[n=slot*8+j][l=i*16+lr], slot=ks*4+lg
    int ra[2][8];
    int raA[2];
#pragma unroll
    for (int i = 0; i < 8; ++i) {
        int l = i * 16 + lr;
        int key = (l ^ (l >> 2)) & 7;
#pragma unroll
        for (int ks = 0; ks < 2; ++ks)
            ra[ks][i] = l * (K1_S * 2) + ((((ks * 4 + lg) ^ key)) << 4);
    }
    {
        int l = w * 16 + lr;        // A-fragment row block = wave id
        int key = (l ^ (l >> 2)) & 7;
#pragma unroll
        for (int ks = 0; ks < 2; ++ks)
            raA[ks] = l * (K1_S * 2) + ((((ks * 4 + lg) ^ key)) << 4);
    }

    f32x4 acc[8];
#pragma unroll
    for (int m = 0; m < 8; ++m) acc[m] = (f32x4)0.f;

    for (int s = 0; s < K1_CHUNK; s += K1_S) {
        __syncthreads();
        float4 v0 = *(const float4*)(gp);
        float4 v1 = *(const float4*)(gp + L_DIM);
        float4 v2 = *(const float4*)(gp + 2 * L_DIM);
        float4 v3 = *(const float4*)(gp + 3 * L_DIM);
        gp += (size_t)K1_S * L_DIM;
        // column-wise pack: transpose comes free with cvt_pk
        *(uint2*)((char*)lds + wb[0]) = make_uint2(pk2(v0.x, v1.x), pk2(v2.x, v3.x));
        *(uint2*)((char*)lds + wb[1]) = make_uint2(pk2(v0.y, v1.y), pk2(v2.y, v3.y));
        *(uint2*)((char*)lds + wb[2]) = make_uint2(pk2(v0.z, v1.z), pk2(v2.z, v3.z));
        *(uint2*)((char*)lds + wb[3]) = make_uint2(pk2(v0.w, v1.w), pk2(v2.w, v3.w));
        __syncthreads();
#pragma unroll
        for (int ks = 0; ks < 2; ++ks) {
            bf16x8 af = *(bf16x8*)((char*)lds + raA[ks]);
            bf16x8 f[8];
#pragma unroll
            for (int i = 0; i < 8; ++i)
                f[i] = *(bf16x8*)((char*)lds + ra[ks][i]);
#pragma unroll
            for (int m = 0; m < 8; ++m)
                acc[m] = __builtin_amdgcn_mfma_f32_16x16x32_bf16(af, f[m], acc[m], 0, 0, 0);
        }
    }

    float* eb = energy + (size_t)b * L_DIM * L_DIM;
    const int row0 = w * 16 + lg * 4;
#pragma unroll
    for (int m = 0; m < 8; ++m)
#pragma unroll
        for (int r2 = 0; r2 < 4; ++r2)
            atomicAdd(&eb[(size_t)(row0 + r2) * L_DIM + m * 16 + lr], acc[m][r2]);
}

// ---------------- Kernel 2: softmax over m; write attnT[b][m][l] as bf16 ----------------
__global__ __launch_bounds__(64) void softmax_kernel(const float* __restrict__ energy,
                                                     short* __restrict__ attnT) {
    const int row = blockIdx.x;  // b*128 + l
    const int b = row >> 7;
    const int l = row & 127;
    const float* e = energy + (size_t)row * L_DIM;
    const int t = threadIdx.x;
    float v0 = e[t];
    float v1 = e[t + 64];
    float mx = fmaxf(v0, v1);
#pragma unroll
    for (int o = 32; o > 0; o >>= 1) mx = fmaxf(mx, __shfl_xor(mx, o));
    float e0 = __expf(v0 - mx);
    float e1 = __expf(v1 - mx);
    float sm = e0 + e1;
#pragma unroll
    for (int o = 32; o > 0; o >>= 1) sm += __shfl_xor(sm, o);
    float inv = 1.0f / sm;
    short* at = attnT + (size_t)b * L_DIM * L_DIM;
    at[(size_t)t * L_DIM + l] = f2bf(e0 * inv);
    at[(size_t)(t + 64) * L_DIM + l] = f2bf(e1 * inv);
}

// ---------------- Kernel 3: out[b,n,m] = sum_l q[b,n,l]*attn[b,l,m] ----------------
#define K3_ROWS 128

__global__ __launch_bounds__(256) void pv_kernel(const float* __restrict__ x,
                                                 const short* __restrict__ attnT,
                                                 float* __restrict__ out) {
    const int wg = blockIdx.x;
    const int chunks = N_PER_B / K3_ROWS;  // 512
    const int b = wg / chunks;
    const int chunk = wg % chunks;
    const float* q = x + (size_t)b * N_PER_B * L_DIM + (size_t)chunk * K3_ROWS * L_DIM;
    float* o = out + (size_t)b * N_PER_B * L_DIM + (size_t)chunk * K3_ROWS * L_DIM;
    const short* at = attnT + (size_t)b * L_DIM * L_DIM;

    // ldsA[n][l], ldsB[m][l]; byte = r*256 + l*2, swizzled ^((r&7)<<4)
    __shared__ short ldsA[K3_ROWS * L_DIM];
    __shared__ short ldsB[L_DIM * L_DIM];

    const int tid = threadIdx.x;
    const int wid = tid >> 6;
    const int lane = tid & 63;
    const int lr = lane & 15;
    const int lg = lane >> 4;

#pragma unroll
    for (int it = 0; it < 8; ++it) {
        int idx = tid + it * 256;
        int n = idx >> 4;            // 0..127
        int l0 = (idx & 15) << 3;    // 0..120
        float4 ra = *(const float4*)(q + (size_t)n * L_DIM + l0);
        float4 rb = *(const float4*)(q + (size_t)n * L_DIM + l0 + 4);
        uint4 p = make_uint4(pk2(ra.x, ra.y), pk2(ra.z, ra.w),
                             pk2(rb.x, rb.y), pk2(rb.z, rb.w));
        int byte = (n * 256 + l0 * 2) ^ ((n & 7) << 4);
        *(uint4*)((char*)ldsA + byte) = p;

        uint4 v = *(const uint4*)(at + (size_t)n * L_DIM + l0);
        *(uint4*)((char*)ldsB + byte) = v;
    }
    __syncthreads();

    f32x4 acc[2][8];
#pragma unroll
    for (int a = 0; a < 2; ++a)
#pragma unroll
        for (int m = 0; m < 8; ++m) acc[a][m] = (f32x4)0.f;

#pragma unroll
    for (int ks = 0; ks < 4; ++ks) {
        int kbyte = ks * 64 + (lg << 4);
        bf16x8 afr[2], bfr[8];
#pragma unroll
        for (int a = 0; a < 2; ++a) {
            int n = (wid * 2 + a) * 16 + lr;
            int byte = (n * 256 + kbyte) ^ ((n & 7) << 4);
            afr[a] = *(bf16x8*)((char*)ldsA + byte);
        }
#pragma unroll
        for (int m = 0; m < 8; ++m) {
            int mm = m * 16 + lr;
            int byte = (mm * 256 + kbyte) ^ ((mm & 7) << 4);
            bfr[m] = *(bf16x8*)((char*)ldsB + byte);
        }
#pragma unroll
        for (int a = 0; a < 2; ++a)
#pragma unroll
            for (int m = 0; m < 8; ++m)
                acc[a][m] = __builtin_amdgcn_mfma_f32_16x16x32_bf16(afr[a], bfr[m], acc[a][m], 0, 0, 0);
    }

#pragma unroll
    for (int a = 0; a < 2; ++a) {
        int row0 = (wid * 2 + a) * 16 + lg * 4;
#pragma unroll
        for (int m = 0; m < 8; ++m)
#pragma unroll
            for (int r2 = 0; r2 < 4; ++r2)
                o[(size_t)(row0 + r2) * L_DIM + m * 16 + lr] = acc[a][m][r2];
    }
}

extern "C" void kernel_launch(void* const* d_in, const int* in_sizes, int n_in,
                              void* d_out, int out_size, void* d_ws, size_t ws_size,
                              hipStream_t stream) {
    const float* x = (const float*)d_in[0];
    float* out = (float*)d_out;
    float* energy = (float*)d_ws;                                               // 512 KB
    short* attnT = (short*)((char*)d_ws + (size_t)BATCH * L_DIM * L_DIM * 4);   // 256 KB

    hipMemsetAsync(energy, 0, (size_t)BATCH * L_DIM * L_DIM * sizeof(float), stream);
    hipLaunchKernelGGL(energy_kernel, dim3(BATCH * (N_PER_B / K1_CHUNK)), dim3(512), 0, stream,
                       x, energy);
    hipLaunchKernelGGL(softmax_kernel, dim3(BATCH * L_DIM), dim3(64), 0, stream,
                       energy, attnT);
    hipLaunchKernelGGL(pv_kernel, dim3(BATCH * (N_PER_B / K3_ROWS)), dim3(256), 0, stream,
                       x, attnT, out);
}

// Round 3
// 175.293 us; speedup vs baseline: 1.7906x; 1.1101x over previous
//
#include <hip/hip_runtime.h>
#include <hip/hip_bf16.h>

#define L_DIM 128
#define N_PER_B 65536
#define BATCH 8

typedef __attribute__((ext_vector_type(8))) short bf16x8;
typedef __attribute__((ext_vector_type(4))) float f32x4;

__device__ __forceinline__ short f2bf(float f) {
    unsigned u = __float_as_uint(f);
    u += 0x7fffu + ((u >> 16) & 1u);   // round-to-nearest-even
    return (short)(u >> 16);
}

// packed f32x2 -> bf16x2 (RNE), maps to v_cvt_pk_bf16_f32
__device__ __forceinline__ unsigned pk2(float a, float b) {
    union { __hip_bfloat162 h; unsigned u; } cvt;
    cvt.h = __float22bfloat162_rn(float2{a, b});
    return cvt.u;
}

// swizzle keys
#define KEY1(n) (((n) >> 2) & 31)            // fp32 staging tile: 16B-granule XOR within 512B row
#define KEY2(l) ((((l) ^ ((l) >> 2)) & 7))   // bf16 tile (round-2 verified)

__device__ __forceinline__ void gld16(const float* g, float* l) {
    __builtin_amdgcn_global_load_lds(
        (const __attribute__((address_space(1))) void*)g,
        (__attribute__((address_space(3))) void*)l, 16, 0, 0);
}

// ---------------- Kernel 1: partial[wg][l][m] = sum_{n in chunk} q[n,l]*q[n,m] ----------------
// 512 blocks x 512 thr (8 waves). Chunk = 1024 rows, 16 steps of 64 rows.
// fbuf: 2 x 32KB fp32 [64n][128l] staged via global_load_lds (src pre-swizzled KEY1).
// bbuf: 16KB bf16 [128l][64n] (KEY2 swizzle) built by in-LDS transpose+cvt_pk pass.
__global__ __launch_bounds__(512, 4) void energy_kernel(const float* __restrict__ x,
                                                        float* __restrict__ partial) {
    const int wg = blockIdx.x;
    const int b = wg >> 6;
    const int chunk = wg & 63;
    const float* q = x + (size_t)b * N_PER_B * L_DIM + (size_t)chunk * 1024 * L_DIM;

    __shared__ float fbuf[2][64 * 128];   // 2 x 32 KB
    __shared__ short bbuf[128 * 64];      // 16 KB

    const int tid = threadIdx.x;
    const int w = tid >> 6;
    const int lane = tid & 63;
    const int lr = lane & 15;
    const int lg = lane >> 4;

    // ---- staging addrs: wave w copies rows 8w..8w+7; instr i covers rows n0i,n0i+1 (1 KB)
    const int sr = lane >> 5;   // which of the 2 rows
    const int sc = lane & 31;   // 16B granule within 512B row
    int so[4], dof[4];
#pragma unroll
    for (int i = 0; i < 4; ++i) {
        int n0i = w * 8 + i * 2;
        int n = n0i + sr;
        so[i] = n * 128 + ((sc ^ KEY1(n)) << 2);   // per-lane pre-swizzled global float offset
        dof[i] = n0i * 128;                        // wave-uniform LDS float offset
    }

    // ---- transpose-pass addrs: thread handles 4n x 4l
    const int n0t = (tid & 15) * 4;
    const int l0t = (tid >> 4) * 4;
    int trd[4], twr[4];
#pragma unroll
    for (int r2 = 0; r2 < 4; ++r2) {
        int n = n0t + r2;
        trd[r2] = n * 128 + (((l0t >> 2) ^ KEY1(n)) << 2);
    }
#pragma unroll
    for (int cc = 0; cc < 4; ++cc) {
        int l = l0t + cc;
        twr[cc] = (l * 128 + n0t * 2) ^ (KEY2(l) << 4);
    }

    // ---- fragment read addrs (bf16 tile, same as round-2)
    int raA[2], ra[2][8];
    {
        int l = w * 16 + lr;
#pragma unroll
        for (int ks = 0; ks < 2; ++ks)
            raA[ks] = l * 128 + (((ks * 4 + lg) ^ KEY2(l)) << 4);
    }
#pragma unroll
    for (int i = 0; i < 8; ++i) {
        int l = i * 16 + lr;
#pragma unroll
        for (int ks = 0; ks < 2; ++ks)
            ra[ks][i] = l * 128 + (((ks * 4 + lg) ^ KEY2(l)) << 4);
    }

    f32x4 acc[8];
#pragma unroll
    for (int m = 0; m < 8; ++m) acc[m] = (f32x4)0.f;

#define K1_ISSUE(bufi, step) do {                                   \
        const float* qs_ = q + (size_t)(step) * (64 * 128);         \
        _Pragma("unroll")                                           \
        for (int i_ = 0; i_ < 4; ++i_)                              \
            gld16(qs_ + so[i_], &fbuf[bufi][dof[i_]]);              \
    } while (0)

    K1_ISSUE(0, 0);
    K1_ISSUE(1, 1);

    for (int t = 0; t < 16; ++t) {
        if (t < 15) { asm volatile("s_waitcnt vmcnt(4) lgkmcnt(0)" ::: "memory"); }
        else        { asm volatile("s_waitcnt vmcnt(0) lgkmcnt(0)" ::: "memory"); }
        __builtin_amdgcn_sched_barrier(0);
        __builtin_amdgcn_s_barrier();            // fp32 buf[t&1] staged; prev compute done
        const int bufi = t & 1;

        // transpose + convert: fbuf[bufi] -> bbuf
        {
            float f4[4][4];
#pragma unroll
            for (int r2 = 0; r2 < 4; ++r2)
                *(float4*)&f4[r2][0] = *(const float4*)&fbuf[bufi][trd[r2]];
#pragma unroll
            for (int cc = 0; cc < 4; ++cc) {
                uint2 u = make_uint2(pk2(f4[0][cc], f4[1][cc]), pk2(f4[2][cc], f4[3][cc]));
                *(uint2*)((char*)bbuf + twr[cc]) = u;
            }
        }
        asm volatile("s_waitcnt lgkmcnt(0)" ::: "memory");
        __builtin_amdgcn_sched_barrier(0);
        __builtin_amdgcn_s_barrier();            // bbuf ready; fbuf[bufi] free for reuse

        if (t + 2 < 16) K1_ISSUE(bufi, t + 2);   // async prefetch 2 steps ahead

#pragma unroll
        for (int ks = 0; ks < 2; ++ks) {
            bf16x8 af = *(bf16x8*)((char*)bbuf + raA[ks]);
            bf16x8 fB[8];
#pragma unroll
            for (int i = 0; i < 8; ++i)
                fB[i] = *(bf16x8*)((char*)bbuf + ra[ks][i]);
#pragma unroll
            for (int m = 0; m < 8; ++m)
                acc[m] = __builtin_amdgcn_mfma_f32_16x16x32_bf16(af, fB[m], acc[m], 0, 0, 0);
        }
    }
#undef K1_ISSUE

    // non-atomic partial store (private 64 KB slot per block)
    float* pb = partial + (size_t)wg * (L_DIM * L_DIM);
    const int row0 = w * 16 + lg * 4;
#pragma unroll
    for (int m = 0; m < 8; ++m)
#pragma unroll
        for (int r2 = 0; r2 < 4; ++r2)
            pb[(size_t)(row0 + r2) * L_DIM + m * 16 + lr] = acc[m][r2];
}

// ---------------- Kernel 2: reduce 64 partials + softmax; write attnT[b][m][l] bf16 ----------------
__global__ __launch_bounds__(64) void reduce_softmax_kernel(const float* __restrict__ partial,
                                                            short* __restrict__ attnT) {
    const int row = blockIdx.x;          // b*128 + l
    const int b = row >> 7;
    const int l = row & 127;
    const int t = threadIdx.x;
    const float* p = partial + (size_t)b * 64 * 16384 + (size_t)l * 128;
    float v0 = 0.f, v1 = 0.f;
#pragma unroll 4
    for (int c = 0; c < 64; ++c) {
        v0 += p[(size_t)c * 16384 + t];
        v1 += p[(size_t)c * 16384 + t + 64];
    }
    float mx = fmaxf(v0, v1);
#pragma unroll
    for (int o = 32; o > 0; o >>= 1) mx = fmaxf(mx, __shfl_xor(mx, o));
    float e0 = __expf(v0 - mx);
    float e1 = __expf(v1 - mx);
    float sm = e0 + e1;
#pragma unroll
    for (int o = 32; o > 0; o >>= 1) sm += __shfl_xor(sm, o);
    float inv = 1.0f / sm;
    short* at = attnT + (size_t)b * L_DIM * L_DIM;
    at[(size_t)t * L_DIM + l] = f2bf(e0 * inv);
    at[(size_t)(t + 64) * L_DIM + l] = f2bf(e1 * inv);
}

// ---------------- Kernel 3: out[b,n,m] = sum_l q[b,n,l]*attn[b,l,m] ----------------
#define K3_ROWS 128

__global__ __launch_bounds__(256) void pv_kernel(const float* __restrict__ x,
                                                 const short* __restrict__ attnT,
                                                 float* __restrict__ out) {
    const int nwg = BATCH * (N_PER_B / K3_ROWS);
    const int wg = nwg - 1 - blockIdx.x;   // reversed: read x tail-first (L3-warm after K1)
    const int chunks = N_PER_B / K3_ROWS;  // 512
    const int b = wg / chunks;
    const int chunk = wg % chunks;
    const float* q = x + (size_t)b * N_PER_B * L_DIM + (size_t)chunk * K3_ROWS * L_DIM;
    float* o = out + (size_t)b * N_PER_B * L_DIM + (size_t)chunk * K3_ROWS * L_DIM;
    const short* at = attnT + (size_t)b * L_DIM * L_DIM;

    __shared__ short ldsA[K3_ROWS * L_DIM];
    __shared__ short ldsB[L_DIM * L_DIM];

    const int tid = threadIdx.x;
    const int wid = tid >> 6;
    const int lane = tid & 63;
    const int lr = lane & 15;
    const int lg = lane >> 4;

#pragma unroll
    for (int it = 0; it < 8; ++it) {
        int idx = tid + it * 256;
        int n = idx >> 4;            // 0..127
        int l0 = (idx & 15) << 3;    // 0..120
        float4 ra = *(const float4*)(q + (size_t)n * L_DIM + l0);
        float4 rb = *(const float4*)(q + (size_t)n * L_DIM + l0 + 4);
        uint4 p = make_uint4(pk2(ra.x, ra.y), pk2(ra.z, ra.w),
                             pk2(rb.x, rb.y), pk2(rb.z, rb.w));
        int byte = (n * 256 + l0 * 2) ^ ((n & 7) << 4);
        *(uint4*)((char*)ldsA + byte) = p;

        uint4 v = *(const uint4*)(at + (size_t)n * L_DIM + l0);
        *(uint4*)((char*)ldsB + byte) = v;
    }
    __syncthreads();

    f32x4 acc[2][8];
#pragma unroll
    for (int a = 0; a < 2; ++a)
#pragma unroll
        for (int m = 0; m < 8; ++m) acc[a][m] = (f32x4)0.f;

#pragma unroll
    for (int ks = 0; ks < 4; ++ks) {
        int kbyte = ks * 64 + (lg << 4);
        bf16x8 afr[2], bfr[8];
#pragma unroll
        for (int a = 0; a < 2; ++a) {
            int n = (wid * 2 + a) * 16 + lr;
            int byte = (n * 256 + kbyte) ^ ((n & 7) << 4);
            afr[a] = *(bf16x8*)((char*)ldsA + byte);
        }
#pragma unroll
        for (int m = 0; m < 8; ++m) {
            int mm = m * 16 + lr;
            int byte = (mm * 256 + kbyte) ^ ((mm & 7) << 4);
            bfr[m] = *(bf16x8*)((char*)ldsB + byte);
        }
#pragma unroll
        for (int a = 0; a < 2; ++a)
#pragma unroll
            for (int m = 0; m < 8; ++m)
                acc[a][m] = __builtin_amdgcn_mfma_f32_16x16x32_bf16(afr[a], bfr[m], acc[a][m], 0, 0, 0);
    }

#pragma unroll
    for (int a = 0; a < 2; ++a) {
        int row0 = (wid * 2 + a) * 16 + lg * 4;
#pragma unroll
        for (int m = 0; m < 8; ++m)
#pragma unroll
            for (int r2 = 0; r2 < 4; ++r2)
                o[(size_t)(row0 + r2) * L_DIM + m * 16 + lr] = acc[a][m][r2];
    }
}

extern "C" void kernel_launch(void* const* d_in, const int* in_sizes, int n_in,
                              void* d_out, int out_size, void* d_ws, size_t ws_size,
                              hipStream_t stream) {
    const float* x = (const float*)d_in[0];
    float* out = (float*)d_out;
    float* partial = (float*)d_ws;                                   // 512 x 64 KB = 32 MB
    short* attnT = (short*)((char*)d_ws + (size_t)512 * 16384 * 4);  // 256 KB

    hipLaunchKernelGGL(energy_kernel, dim3(512), dim3(512), 0, stream, x, partial);
    hipLaunchKernelGGL(reduce_softmax_kernel, dim3(BATCH * L_DIM), dim3(64), 0, stream,
                       partial, attnT);
    hipLaunchKernelGGL(pv_kernel, dim3(BATCH * (N_PER_B / K3_ROWS)), dim3(256), 0, stream,
                       x, attnT, out);
}

// Round 5
// 170.784 us; speedup vs baseline: 1.8378x; 1.0264x over previous
//
#include <hip/hip_runtime.h>
#include <hip/hip_bf16.h>

#define L_DIM 128
#define N_PER_B 65536
#define BATCH 8

typedef __attribute__((ext_vector_type(8))) short bf16x8;
typedef __attribute__((ext_vector_type(4))) float f32x4;

__device__ __forceinline__ short f2bf(float f) {
    unsigned u = __float_as_uint(f);
    u += 0x7fffu + ((u >> 16) & 1u);   // round-to-nearest-even
    return (short)(u >> 16);
}

// packed f32x2 -> bf16x2 (RNE), maps to v_cvt_pk_bf16_f32
__device__ __forceinline__ unsigned pk2(float a, float b) {
    union { __hip_bfloat162 h; unsigned u; } cvt;
    cvt.h = __float22bfloat162_rn(float2{a, b});
    return cvt.u;
}

#define KEY2(l) ((((l) ^ ((l) >> 2)) & 7))   // bf16 [l][n] tile swizzle (rounds 2-3 verified)

// ---------------- Kernel 1: partial[wg][l][m] = sum_{n in chunk} q[n,l]*q[n,m] ----------------
// 512 blocks x 512 thr. Chunk = 1024 rows, 16 steps of 64 rows.
// Register staging + cvt_pk free transpose -> 2 x 16KB bf16 [l][n] dbuf, 1 barrier/step.
__global__ __launch_bounds__(512, 4) void energy_kernel(const float* __restrict__ x,
                                                        float* __restrict__ partial) {
    const int wg = blockIdx.x;
    const int b = wg >> 6;
    const int chunk = wg & 63;
    const float* qblk = x + (size_t)b * N_PER_B * L_DIM + (size_t)chunk * 1024 * L_DIM;

    __shared__ short bbuf[2][L_DIM * 64];   // 2 x 16 KB

    const int tid = threadIdx.x;
    const int w = tid >> 6;
    const int lane = tid & 63;
    const int lr = lane & 15;
    const int lg = lane >> 4;

    // staging: thread covers rows n0,n0+1 x cols c0..c0+7 (32B/lane coalesced)
    const int n0 = (tid >> 4) * 2;       // 0..62
    const int c0 = (tid & 15) * 8;       // 0..120
    const float* g = qblk + (size_t)n0 * L_DIM + c0;

    int wb[8];
#pragma unroll
    for (int j = 0; j < 8; ++j) {
        int l = c0 + j;
        wb[j] = (l * 128 + n0 * 2) ^ (KEY2(l) << 4);
    }

    // fragment read addrs (ks=0); ks=1 = ^0x40 (granule bit 2 flip, lg<4, key<8)
    int raA0, ra0[8];
    {
        int l = w * 16 + lr;
        raA0 = l * 128 + ((lg ^ KEY2(l)) << 4);
    }
#pragma unroll
    for (int i = 0; i < 8; ++i) {
        int l = i * 16 + lr;
        ra0[i] = l * 128 + ((lg ^ KEY2(l)) << 4);
    }

    f32x4 acc[8];
#pragma unroll
    for (int m = 0; m < 8; ++m) acc[m] = (f32x4)0.f;

    float4 ra_[4], rb_[4];   // [0..1] = row n0 (8 floats), [2..3] = row n0+1

#define K1_LOAD(R, step) do {                                   \
        const float* gs_ = g + (size_t)(step) * (64 * L_DIM);   \
        R[0] = *(const float4*)(gs_);                           \
        R[1] = *(const float4*)(gs_ + 4);                       \
        R[2] = *(const float4*)(gs_ + L_DIM);                   \
        R[3] = *(const float4*)(gs_ + L_DIM + 4);               \
    } while (0)

#define K1_CVT(R, buf) do {                                     \
        const float* r0_ = (const float*)&R[0];                 \
        const float* r1_ = (const float*)&R[2];                 \
        _Pragma("unroll")                                       \
        for (int j_ = 0; j_ < 8; ++j_)                          \
            *(unsigned*)((char*)(buf) + wb[j_]) = pk2(r0_[j_], r1_[j_]); \
    } while (0)

#define K1_MFMA(buf) do {                                                       \
        _Pragma("unroll")                                                       \
        for (int ks_ = 0; ks_ < 2; ++ks_) {                                     \
            bf16x8 af_ = *(bf16x8*)((char*)(buf) + (raA0 ^ (ks_ << 6)));        \
            bf16x8 fB_[8];                                                      \
            _Pragma("unroll")                                                   \
            for (int i_ = 0; i_ < 8; ++i_)                                      \
                fB_[i_] = *(bf16x8*)((char*)(buf) + (ra0[i_] ^ (ks_ << 6)));    \
            _Pragma("unroll")                                                   \
            for (int m_ = 0; m_ < 8; ++m_)                                      \
                acc[m_] = __builtin_amdgcn_mfma_f32_16x16x32_bf16(af_, fB_[m_], acc[m_], 0, 0, 0); \
        }                                                                       \
    } while (0)

#define K1_BAR() do {                                           \
        asm volatile("s_waitcnt lgkmcnt(0)" ::: "memory");      \
        __builtin_amdgcn_sched_barrier(0);                      \
        __builtin_amdgcn_s_barrier();                           \
    } while (0)

    K1_LOAD(ra_, 0);
    K1_CVT(ra_, bbuf[0]);        // tile0 -> bbuf0 (vmcnt auto via reg deps)
    K1_LOAD(rb_, 1);             // tile1 in flight across barrier (no vmcnt drain)
    K1_BAR();

    for (int tt = 0; tt < 16; tt += 2) {
        K1_MFMA(bbuf[0]);                    // tile tt
        if (tt < 14) K1_LOAD(ra_, tt + 2);
        K1_CVT(rb_, bbuf[1]);                // tile tt+1 -> bbuf1
        K1_BAR();
        K1_MFMA(bbuf[1]);                    // tile tt+1
        if (tt < 14) {
            K1_LOAD(rb_, tt + 3);
            K1_CVT(ra_, bbuf[0]);            // tile tt+2 -> bbuf0
            K1_BAR();
        }
    }
#undef K1_LOAD
#undef K1_CVT
#undef K1_MFMA
#undef K1_BAR

    float* pb = partial + (size_t)wg * (L_DIM * L_DIM);
    const int row0 = w * 16 + lg * 4;
#pragma unroll
    for (int m = 0; m < 8; ++m)
#pragma unroll
        for (int r2 = 0; r2 < 4; ++r2)
            pb[(size_t)(row0 + r2) * L_DIM + m * 16 + lr] = acc[m][r2];
}

// ---------------- Kernel 2: reduce 64 partials + softmax; write attnT[b][m][l] bf16 ----------------
__global__ __launch_bounds__(64) void reduce_softmax_kernel(const float* __restrict__ partial,
                                                            short* __restrict__ attnT) {
    const int row = blockIdx.x;          // b*128 + l
    const int b = row >> 7;
    const int l = row & 127;
    const int t = threadIdx.x;
    const float* p = partial + (size_t)b * 64 * 16384 + (size_t)l * 128;
    float v0 = 0.f, v1 = 0.f;
#pragma unroll 4
    for (int c = 0; c < 64; ++c) {
        v0 += p[t];
        v1 += p[t + 64];
        p += 16384;
    }
    float mx = fmaxf(v0, v1);
#pragma unroll
    for (int o = 32; o > 0; o >>= 1) mx = fmaxf(mx, __shfl_xor(mx, o));
    float e0 = __expf(v0 - mx);
    float e1 = __expf(v1 - mx);
    float sm = e0 + e1;
#pragma unroll
    for (int o = 32; o > 0; o >>= 1) sm += __shfl_xor(sm, o);
    float inv = 1.0f / sm;
    short* at = attnT + (size_t)b * L_DIM * L_DIM;
    at[(size_t)t * L_DIM + l] = f2bf(e0 * inv);
    at[(size_t)(t + 64) * L_DIM + l] = f2bf(e1 * inv);
}

// ---------------- Kernel 3: out[n,m] = sum_l q[n,l]*attn[l,m] ----------------
// 512 blocks x 512 thr, 1024 rows/block; attn tile loaded ONCE per block; reversed for L3 reuse.
__global__ __launch_bounds__(512, 4) void pv_kernel(const float* __restrict__ x,
                                                    const short* __restrict__ attnT,
                                                    float* __restrict__ out) {
    const int wg = 511 - blockIdx.x;     // reversed: read x tail-first (L3-warm after K1)
    const int b = wg >> 6;
    const int chunk = wg & 63;
    const float* qblk = x + (size_t)b * N_PER_B * L_DIM + (size_t)chunk * 1024 * L_DIM;
    float* oblk = out + (size_t)b * N_PER_B * L_DIM + (size_t)chunk * 1024 * L_DIM;
    const short* at = attnT + (size_t)b * 16384;

    __shared__ short ldsA[128 * L_DIM];  // 32 KB x rows (bf16, swizzled)
    __shared__ short ldsB[L_DIM * L_DIM];// 32 KB attnT tile (bf16, swizzled)

    const int tid = threadIdx.x;
    const int w = tid >> 6;
    const int lane = tid & 63;
    const int lr = lane & 15;
    const int lg = lane >> 4;

    // load attn tile once per block
#pragma unroll
    for (int it = 0; it < 4; ++it) {
        int idx = tid + it * 512;
        int n = idx >> 4;                // 0..127
        int l0i = (idx & 15) << 3;
        uint4 v = *(const uint4*)(at + (size_t)n * 128 + l0i);
        int byte = (n * 256 + l0i * 2) ^ ((n & 7) << 4);
        *(uint4*)((char*)ldsB + byte) = v;
    }

    for (int stt = 0; stt < 8; ++stt) {
        const int st = 7 - stt;          // freshest x first
        const float* qs = qblk + (size_t)st * 128 * L_DIM;
        float* os = oblk + (size_t)st * 128 * L_DIM;

        __syncthreads();                 // prev MFMA reads done (covers ldsB load at stt=0)
#pragma unroll
        for (int it = 0; it < 4; ++it) {
            int idx = tid + it * 512;
            int n = idx >> 4;
            int l0i = (idx & 15) << 3;
            float4 ra = *(const float4*)(qs + (size_t)n * L_DIM + l0i);
            float4 rb = *(const float4*)(qs + (size_t)n * L_DIM + l0i + 4);
            uint4 pk = make_uint4(pk2(ra.x, ra.y), pk2(ra.z, ra.w),
                                  pk2(rb.x, rb.y), pk2(rb.z, rb.w));
            int byte = (n * 256 + l0i * 2) ^ ((n & 7) << 4);
            *(uint4*)((char*)ldsA + byte) = pk;
        }
        __syncthreads();

        f32x4 acc[8];
#pragma unroll
        for (int m = 0; m < 8; ++m) acc[m] = (f32x4)0.f;

#pragma unroll
        for (int ks = 0; ks < 4; ++ks) {
            int kbyte = ks * 64 + (lg << 4);
            int n = w * 16 + lr;
            bf16x8 afr = *(bf16x8*)((char*)ldsA + ((n * 256 + kbyte) ^ ((n & 7) << 4)));
            bf16x8 bfr[8];
#pragma unroll
            for (int m = 0; m < 8; ++m) {
                int mm = m * 16 + lr;
                bfr[m] = *(bf16x8*)((char*)ldsB + ((mm * 256 + kbyte) ^ ((mm & 7) << 4)));
            }
#pragma unroll
            for (int m = 0; m < 8; ++m)
                acc[m] = __builtin_amdgcn_mfma_f32_16x16x32_bf16(afr, bfr[m], acc[m], 0, 0, 0);
        }

        const int row0 = w * 16 + lg * 4;
#pragma unroll
        for (int m = 0; m < 8; ++m)
#pragma unroll
            for (int r2 = 0; r2 < 4; ++r2)
                os[(size_t)(row0 + r2) * L_DIM + m * 16 + lr] = acc[m][r2];
    }
}

extern "C" void kernel_launch(void* const* d_in, const int* in_sizes, int n_in,
                              void* d_out, int out_size, void* d_ws, size_t ws_size,
                              hipStream_t stream) {
    const float* x = (const float*)d_in[0];
    float* out = (float*)d_out;
    float* partial = (float*)d_ws;                                   // 512 x 64 KB = 32 MB
    short* attnT = (short*)((char*)d_ws + (size_t)512 * 16384 * 4);  // 256 KB

    hipLaunchKernelGGL(energy_kernel, dim3(512), dim3(512), 0, stream, x, partial);
    hipLaunchKernelGGL(reduce_softmax_kernel, dim3(BATCH * L_DIM), dim3(64), 0, stream,
                       partial, attnT);
    hipLaunchKernelGGL(pv_kernel, dim3(512), dim3(512), 0, stream, x, attnT, out);
}